// Round 9
// baseline (381.838 us; speedup 1.0000x reference)
//
#include <hip/hip_runtime.h>
#include <hip/hip_fp16.h>
#include <math.h>

#define N_NODES 100000
#define N_EDGES 800000
#define C 64
#define SLOT 32            // fine bins per node (Poisson(8): P(deg>=33) ~ 6e-28)
#define NB 391             // coarse buckets of 256 node ids (391*256 >= 100000)
#define CAP 2560           // coarse bucket capacity (mean 2048, +11 sigma)
#define SC_BLOCKS 196      // 196 blocks * 4096 edges = 802,816 >= N_EDGES
#define EPT 16             // edges per thread in scatter
#define G4_BLOCKS 1563     // 1563 blocks * 64 rows = 100,032 >= N_NODES (quarter-wave GEMM)

#define XCOMP(v, c) ((c) == 0 ? (v).x : (c) == 1 ? (v).y : (c) == 2 ? (v).z : (v).w)

__device__ inline unsigned pk2h(float a, float b) {
    __half2 h = __floats2half2_rn(a, b);
    return *(unsigned*)&h;
}

// ---- merged: blocks [0,SC_BLOCKS): block-aggregated coarse bucket scatter;
//      blocks [SC_BLOCKS,+G4_BLOCKS): hs = x@W (fp16), quarter-wave layout ----
__global__ __launch_bounds__(256, 4) void scatter_xw_kernel(
        const int* __restrict__ src, const int* __restrict__ dst,
        int* __restrict__ cur, unsigned* __restrict__ bdata,
        const float* __restrict__ x, const float* __restrict__ W,
        uint4* __restrict__ hs4) {
    if (blockIdx.x < SC_BLOCKS) {
        __shared__ int hcnt[NB];
        __shared__ int hbase[NB];
        const int blk = blockIdx.x;
        const int tid = threadIdx.x;
        const int e0 = blk * (256 * EPT);

        for (int i = tid; i < NB; i += 256) hcnt[i] = 0;
        __syncthreads();

        int bktA[EPT];
        unsigned keyA[EPT];
#pragma unroll
        for (int i = 0; i < EPT; ++i) {
            const int e = e0 + i * 256 + tid;      // coalesced per i
            int bk = -1; unsigned k = 0;
            if (e < N_EDGES) {
                const int d = dst[e];
                const int s = src[e];
                bk = d >> 8;
                k = ((unsigned)(d & 255) << 17) | (unsigned)s;
                atomicAdd(&hcnt[bk], 1);
            }
            bktA[i] = bk; keyA[i] = k;
        }
        __syncthreads();

        // reserve a contiguous range per non-empty bucket (<=196 atomics/cursor)
        for (int i = tid; i < NB; i += 256) {
            const int c = hcnt[i];
            hbase[i] = c ? atomicAdd(&cur[i * 16], c) : 0;
            hcnt[i] = 0;                           // reuse as local cursor
        }
        __syncthreads();

#pragma unroll
        for (int i = 0; i < EPT; ++i) {
            if (bktA[i] >= 0) {
                const int p = atomicAdd(&hcnt[bktA[i]], 1);   // LDS
                const int pos = hbase[bktA[i]] + p;
                if (pos < CAP) bdata[bktA[i] * CAP + pos] = keyA[i];
            }
        }
        return;
    }
    // ---- xw half: wave w handles channels [w*16, w*16+16) for 64 rows ----
    const int w = threadIdx.x >> 6;
    const int lane = threadIdx.x & 63;
    const int r = (blockIdx.x - SC_BLOCKS) * 64 + lane;
    const bool valid = r < N_NODES;
    const int c0 = w * 16;
    const float4* __restrict__ x4 = (const float4*)x;

    float acc[16];
#pragma unroll
    for (int m = 0; m < 16; ++m) acc[m] = 0.0f;

#pragma unroll
    for (int kk = 0; kk < 4; ++kk) {
        float4 xv[4];
#pragma unroll
        for (int q = 0; q < 4; ++q)
            xv[q] = valid ? x4[r * 16 + kk * 4 + q] : make_float4(0.f, 0.f, 0.f, 0.f);
#pragma unroll
        for (int j = 0; j < 16; ++j) {
            const float xs = XCOMP(xv[j >> 2], j & 3);                  // static
            const float* __restrict__ wr = W + (kk * 16 + j) * C + c0;  // wave-uniform
#pragma unroll
            for (int m = 0; m < 16; ++m) acc[m] = fmaf(xs, wr[m], acc[m]);
        }
    }

    if (valid) {
        uint4 u0, u1;
        u0.x = pk2h(acc[0], acc[1]);  u0.y = pk2h(acc[2], acc[3]);
        u0.z = pk2h(acc[4], acc[5]);  u0.w = pk2h(acc[6], acc[7]);
        u1.x = pk2h(acc[8], acc[9]);  u1.y = pk2h(acc[10], acc[11]);
        u1.z = pk2h(acc[12], acc[13]); u1.w = pk2h(acc[14], acc[15]);
        hs4[r * 8 + w * 2]     = u0;
        hs4[r * 8 + w * 2 + 1] = u1;
    }
}

// ---- fine binning in LDS, coalesced write-out; also cnt + dinv arrays ----
__global__ __launch_bounds__(256) void bin_kernel(
        const int* __restrict__ cur, const unsigned* __restrict__ bdata,
        int* __restrict__ srcs, int* __restrict__ cnt, float* __restrict__ dinv) {
    __shared__ int fcnt[256];
    __shared__ int bins[256 * SLOT];       // 32 KB
    const int b = blockIdx.x;
    const int tid = threadIdx.x;
    const int n0 = b << 8;
    const int nvalid = (N_NODES - n0) < 256 ? (N_NODES - n0) : 256;

    fcnt[tid] = 0;
    __syncthreads();

    const int cb = cur[b * 16] < CAP ? cur[b * 16] : CAP;
    for (int i = tid; i < cb; i += 256) {
        const unsigned w = bdata[b * CAP + i];
        const int id = (int)(w >> 17);
        const int s = (int)(w & 0x1FFFF);
        const int p = atomicAdd(&fcnt[id], 1);
        if (p < SLOT) bins[id * SLOT + p] = s;
    }
    __syncthreads();

    if (tid < nvalid) {
        const int c = fcnt[tid];
        cnt[n0 + tid] = c;
        dinv[n0 + tid] = rsqrtf((float)c + 1.0f);
    }
    const int tot = nvalid * SLOT;
    for (int i = tid; i < tot; i += 256)          // coalesced; garbage never read
        srcs[n0 * SLOT + i] = bins[i];
}

// ---- gather + LN + relu + gate: wave per node, fp16 hs, 8 edges in flight ----
__global__ __launch_bounds__(256) void gather_ln_kernel(
        const uint4* __restrict__ hs4, const int* __restrict__ cnt,
        const float* __restrict__ dinvA, const int* __restrict__ srcs,
        const float4* __restrict__ x4, const float* __restrict__ b,
        const float* __restrict__ gamma, const float* __restrict__ beta,
        float4* __restrict__ g4) {
    const int lane = threadIdx.x & 63;
    const int n = blockIdx.x * 4 + (threadIdx.x >> 6);   // 25000*4 = 100000
    const int eg = lane >> 3;     // edge slot 0..7
    const int cg = lane & 7;      // channel group: channels cg*8 .. cg*8+7

    const int deg = cnt[n];
    const int dg = deg < SLOT ? deg : SLOT;
    const int base = n * SLOT;
    const float dinv = dinvA[n];

    float a[8];
    if (eg == 0) {                // self-loop term: dinv_n * h_n
        const uint4 hv = hs4[n * 8 + cg];
        const float2 f0 = __half22float2(*(const __half2*)&hv.x);
        const float2 f1 = __half22float2(*(const __half2*)&hv.y);
        const float2 f2 = __half22float2(*(const __half2*)&hv.z);
        const float2 f3 = __half22float2(*(const __half2*)&hv.w);
        a[0] = dinv * f0.x; a[1] = dinv * f0.y; a[2] = dinv * f1.x; a[3] = dinv * f1.y;
        a[4] = dinv * f2.x; a[5] = dinv * f2.y; a[6] = dinv * f3.x; a[7] = dinv * f3.y;
    } else {
#pragma unroll
        for (int i = 0; i < 8; ++i) a[i] = 0.0f;
    }

    for (int j = eg; j < dg; j += 8) {
        const int s = srcs[base + j];
        const float ds = dinvA[s];
        const uint4 hv = hs4[s * 8 + cg];
        const float2 f0 = __half22float2(*(const __half2*)&hv.x);
        const float2 f1 = __half22float2(*(const __half2*)&hv.y);
        const float2 f2 = __half22float2(*(const __half2*)&hv.z);
        const float2 f3 = __half22float2(*(const __half2*)&hv.w);
        a[0] = fmaf(ds, f0.x, a[0]); a[1] = fmaf(ds, f0.y, a[1]);
        a[2] = fmaf(ds, f1.x, a[2]); a[3] = fmaf(ds, f1.y, a[3]);
        a[4] = fmaf(ds, f2.x, a[4]); a[5] = fmaf(ds, f2.y, a[5]);
        a[6] = fmaf(ds, f3.x, a[6]); a[7] = fmaf(ds, f3.y, a[7]);
    }

#pragma unroll
    for (int o = 8; o <= 32; o <<= 1) {
#pragma unroll
        for (int i = 0; i < 8; ++i) a[i] += __shfl_xor(a[i], o);
    }

    const float4* __restrict__ b4 = (const float4*)b;
    const float4 b0 = b4[cg * 2], b1 = b4[cg * 2 + 1];

    float t[8];
    t[0] = dinv * a[0] + b0.x; t[1] = dinv * a[1] + b0.y;
    t[2] = dinv * a[2] + b0.z; t[3] = dinv * a[3] + b0.w;
    t[4] = dinv * a[4] + b1.x; t[5] = dinv * a[5] + b1.y;
    t[6] = dinv * a[6] + b1.z; t[7] = dinv * a[7] + b1.w;

    float s1 = t[0] + t[1] + t[2] + t[3] + t[4] + t[5] + t[6] + t[7];
#pragma unroll
    for (int o = 1; o <= 4; o <<= 1) s1 += __shfl_xor(s1, o);
    const float mu = s1 * (1.0f / 64.0f);

    float d[8], s2 = 0.f;
#pragma unroll
    for (int i = 0; i < 8; ++i) { d[i] = t[i] - mu; s2 = fmaf(d[i], d[i], s2); }
#pragma unroll
    for (int o = 1; o <= 4; o <<= 1) s2 += __shfl_xor(s2, o);
    const float rstd = rsqrtf(s2 * (1.0f / 64.0f) + 1e-5f);

    const float4* __restrict__ gm4 = (const float4*)gamma;
    const float4* __restrict__ bt4 = (const float4*)beta;
    const float4 gm0 = gm4[cg * 2], gm1 = gm4[cg * 2 + 1];
    const float4 bt0 = bt4[cg * 2], bt1 = bt4[cg * 2 + 1];
    const float4 xv0 = x4[n * 16 + cg * 2], xv1 = x4[n * 16 + cg * 2 + 1];

    if (eg == 0) {
        float4 o0, o1;
        o0.x = fmaxf(d[0] * rstd * gm0.x + bt0.x, 0.f) * xv0.x;
        o0.y = fmaxf(d[1] * rstd * gm0.y + bt0.y, 0.f) * xv0.y;
        o0.z = fmaxf(d[2] * rstd * gm0.z + bt0.z, 0.f) * xv0.z;
        o0.w = fmaxf(d[3] * rstd * gm0.w + bt0.w, 0.f) * xv0.w;
        o1.x = fmaxf(d[4] * rstd * gm1.x + bt1.x, 0.f) * xv1.x;
        o1.y = fmaxf(d[5] * rstd * gm1.y + bt1.y, 0.f) * xv1.y;
        o1.z = fmaxf(d[6] * rstd * gm1.z + bt1.z, 0.f) * xv1.z;
        o1.w = fmaxf(d[7] * rstd * gm1.w + bt1.w, 0.f) * xv1.w;
        g4[n * 16 + cg * 2]     = o0;
        g4[n * 16 + cg * 2 + 1] = o1;
    }
}

// ---- out = g @ fcW + fcb: quarter-wave; g aliases out (preload + barrier) ----
__global__ __launch_bounds__(256, 4) void fc_kernel(const float* g,
                                                    const float* __restrict__ fcW,
                                                    const float* __restrict__ fcb,
                                                    float* out) {
    const int w = threadIdx.x >> 6;
    const int lane = threadIdx.x & 63;
    const int r = blockIdx.x * 64 + lane;
    const bool valid = r < N_NODES;
    const int c0 = w * 16;
    const float4* g4 = (const float4*)g;

    // preload the full g row before ANY store from this block (rows are
    // block-exclusive; barrier orders all reads before all writes)
    float4 gv[16];
#pragma unroll
    for (int q = 0; q < 16; ++q)
        gv[q] = valid ? g4[r * 16 + q] : make_float4(0.f, 0.f, 0.f, 0.f);
    __syncthreads();

    float acc[16];
    const float4* __restrict__ fcb4 = (const float4*)(fcb + c0);   // wave-uniform
#pragma unroll
    for (int m4 = 0; m4 < 4; ++m4) {
        const float4 bv = fcb4[m4];
        acc[4 * m4 + 0] = bv.x; acc[4 * m4 + 1] = bv.y;
        acc[4 * m4 + 2] = bv.z; acc[4 * m4 + 3] = bv.w;
    }

#pragma unroll
    for (int kk = 0; kk < 4; ++kk) {
#pragma unroll
        for (int j = 0; j < 16; ++j) {
            const float gs = XCOMP(gv[kk * 4 + (j >> 2)], j & 3);         // static
            const float* __restrict__ wr = fcW + (kk * 16 + j) * C + c0;  // wave-uniform
#pragma unroll
            for (int m = 0; m < 16; ++m) acc[m] = fmaf(gs, wr[m], acc[m]);
        }
    }

    if (valid) {
        float4* out4 = (float4*)out;
#pragma unroll
        for (int m4 = 0; m4 < 4; ++m4)
            out4[r * 16 + w * 4 + m4] = make_float4(acc[4 * m4], acc[4 * m4 + 1],
                                                    acc[4 * m4 + 2], acc[4 * m4 + 3]);
    }
}

extern "C" void kernel_launch(void* const* d_in, const int* in_sizes, int n_in,
                              void* d_out, int out_size, void* d_ws, size_t ws_size,
                              hipStream_t stream) {
    const float* x     = (const float*)d_in[0];
    const int*   ei    = (const int*)d_in[1];
    const float* W     = (const float*)d_in[2];
    const float* b     = (const float*)d_in[3];
    const float* gamma = (const float*)d_in[4];
    const float* beta  = (const float*)d_in[5];
    const float* fcW   = (const float*)d_in[6];
    const float* fcb   = (const float*)d_in[7];
    float* out = (float*)d_out;

    const int* srcI = ei;
    const int* dstI = ei + N_EDGES;

    // workspace layout (~30 MB)
    int*      cur   = (int*)d_ws;                   // NB*16 padded cursors (8192 ints)
    unsigned* bdata = (unsigned*)(cur + 8192);      // NB*CAP words (4.0 MB)
    int*      srcs  = (int*)(bdata + NB * CAP);     // N_NODES*SLOT (12.8 MB)
    int*      cnt   = srcs + N_NODES * SLOT;        // 100352
    float*    dinv  = (float*)(cnt + 100352);       // 100352
    uint4*    hs4   = (uint4*)(dinv + 100352);      // N_NODES*C fp16 (12.8 MB)

    float* g = out;                                 // gated activation aliases d_out

    hipMemsetAsync(cur, 0, NB * 16 * sizeof(int), stream);

    scatter_xw_kernel<<<SC_BLOCKS + G4_BLOCKS, 256, 0, stream>>>(srcI, dstI, cur,
                                                                 bdata, x, W, hs4);

    bin_kernel<<<NB, 256, 0, stream>>>(cur, bdata, srcs, cnt, dinv);

    gather_ln_kernel<<<N_NODES / 4, 256, 0, stream>>>(hs4, cnt, dinv, srcs,
                                                      (const float4*)x, b, gamma,
                                                      beta, (float4*)g);

    fc_kernel<<<G4_BLOCKS, 256, 0, stream>>>(g, fcW, fcb, out);
}

// Round 10
// 211.147 us; speedup vs baseline: 1.8084x; 1.8084x over previous
//
#include <hip/hip_runtime.h>
#include <hip/hip_fp16.h>
#include <math.h>

#define N_NODES 100000
#define N_EDGES 800000
#define C 64
#define SLOT 32            // fine bins per node (Poisson(8): P(deg>=33) ~ 6e-28)
#define NB 391             // coarse buckets of 256 node ids (391*256 >= 100000)
#define CAP 2560           // coarse bucket capacity (mean 2048, +11 sigma)
#define SC_BLOCKS 196      // 196 blocks * 4096 edges = 802,816 >= N_EDGES
#define EPT 16             // edges per thread in scatter
#define XW_BLOCKS 391      // 391 blocks * 256 rows = 100,096 >= N_NODES

#define XCOMP(v, c) ((c) == 0 ? (v).x : (c) == 1 ? (v).y : (c) == 2 ? (v).z : (v).w)

__device__ inline unsigned pk2h(float a, float b) {
    __half2 h = __floats2half2_rn(a, b);
    return *(unsigned*)&h;
}

// ---- merged: blocks [0,SC_BLOCKS): block-aggregated coarse bucket scatter;
//      blocks [SC_BLOCKS,+XW_BLOCKS): hs = x@W (fp16), lane-per-row, acc[64],
//      no spill thanks to __launch_bounds__(256,2) (VGPR cap 256) ----
__global__ __launch_bounds__(256, 2) void scatter_xw_kernel(
        const int* __restrict__ src, const int* __restrict__ dst,
        int* __restrict__ cur, unsigned* __restrict__ bdata,
        const float* __restrict__ x, const float* __restrict__ W,
        uint4* __restrict__ hs4) {
    if (blockIdx.x < SC_BLOCKS) {
        __shared__ int hcnt[NB];
        __shared__ int hbase[NB];
        const int blk = blockIdx.x;
        const int tid = threadIdx.x;
        const int e0 = blk * (256 * EPT);

        for (int i = tid; i < NB; i += 256) hcnt[i] = 0;
        __syncthreads();

        int bktA[EPT];
        unsigned keyA[EPT];
#pragma unroll
        for (int i = 0; i < EPT; ++i) {
            const int e = e0 + i * 256 + tid;      // coalesced per i
            int bk = -1; unsigned k = 0;
            if (e < N_EDGES) {
                const int d = dst[e];
                const int s = src[e];
                bk = d >> 8;
                k = ((unsigned)(d & 255) << 17) | (unsigned)s;
                atomicAdd(&hcnt[bk], 1);
            }
            bktA[i] = bk; keyA[i] = k;
        }
        __syncthreads();

        // reserve a contiguous range per non-empty bucket (<=196 atomics/cursor)
        for (int i = tid; i < NB; i += 256) {
            const int c = hcnt[i];
            hbase[i] = c ? atomicAdd(&cur[i * 16], c) : 0;
            hcnt[i] = 0;                           // reuse as local cursor
        }
        __syncthreads();

#pragma unroll
        for (int i = 0; i < EPT; ++i) {
            if (bktA[i] >= 0) {
                const int p = atomicAdd(&hcnt[bktA[i]], 1);   // LDS
                const int pos = hbase[bktA[i]] + p;
                if (pos < CAP) bdata[bktA[i] * CAP + pos] = keyA[i];
            }
        }
        return;
    }
    // ---- xw half: lane owns one full row (64 channels), 256 rows/block ----
    const int lane = threadIdx.x & 63;
    const int wv = (blockIdx.x - SC_BLOCKS) * 4 + (threadIdx.x >> 6);
    const int r = wv * 64 + lane;
    const bool valid = r < N_NODES;
    const float4* __restrict__ x4 = (const float4*)x;

    float acc[C];
#pragma unroll
    for (int m = 0; m < C; ++m) acc[m] = 0.0f;

#pragma unroll
    for (int kk = 0; kk < 4; ++kk) {
        float4 xv[4];
#pragma unroll
        for (int q = 0; q < 4; ++q)
            xv[q] = valid ? x4[r * 16 + kk * 4 + q] : make_float4(0.f, 0.f, 0.f, 0.f);
#pragma unroll
        for (int j = 0; j < 16; ++j) {
            const float xs = XCOMP(xv[j >> 2], j & 3);             // static after unroll
            const float* __restrict__ wr = W + (kk * 16 + j) * C;  // wave-uniform row
#pragma unroll
            for (int m = 0; m < C; ++m) acc[m] = fmaf(xs, wr[m], acc[m]);
        }
    }

    if (valid) {
#pragma unroll
        for (int q = 0; q < 8; ++q) {
            uint4 u;
            u.x = pk2h(acc[8 * q + 0], acc[8 * q + 1]);
            u.y = pk2h(acc[8 * q + 2], acc[8 * q + 3]);
            u.z = pk2h(acc[8 * q + 4], acc[8 * q + 5]);
            u.w = pk2h(acc[8 * q + 6], acc[8 * q + 7]);
            hs4[r * 8 + q] = u;                    // 128 B contiguous per lane
        }
    }
}

// ---- fine binning in LDS, coalesced write-out; also cnt + dinv arrays ----
__global__ __launch_bounds__(256) void bin_kernel(
        const int* __restrict__ cur, const unsigned* __restrict__ bdata,
        int* __restrict__ srcs, int* __restrict__ cnt, float* __restrict__ dinv) {
    __shared__ int fcnt[256];
    __shared__ int bins[256 * SLOT];       // 32 KB
    const int b = blockIdx.x;
    const int tid = threadIdx.x;
    const int n0 = b << 8;
    const int nvalid = (N_NODES - n0) < 256 ? (N_NODES - n0) : 256;

    fcnt[tid] = 0;
    __syncthreads();

    const int cb = cur[b * 16] < CAP ? cur[b * 16] : CAP;
    for (int i = tid; i < cb; i += 256) {
        const unsigned w = bdata[b * CAP + i];
        const int id = (int)(w >> 17);
        const int s = (int)(w & 0x1FFFF);
        const int p = atomicAdd(&fcnt[id], 1);
        if (p < SLOT) bins[id * SLOT + p] = s;
    }
    __syncthreads();

    if (tid < nvalid) {
        const int c = fcnt[tid];
        cnt[n0 + tid] = c;
        dinv[n0 + tid] = rsqrtf((float)c + 1.0f);
    }
    const int tot = nvalid * SLOT;
    for (int i = tid; i < tot; i += 256)          // coalesced; garbage never read
        srcs[n0 * SLOT + i] = bins[i];
}

// ---- gather + LN + relu + gate: wave per node, fp16 hs, 8 edges in flight ----
__global__ __launch_bounds__(256) void gather_ln_kernel(
        const uint4* __restrict__ hs4, const int* __restrict__ cnt,
        const float* __restrict__ dinvA, const int* __restrict__ srcs,
        const float4* __restrict__ x4, const float* __restrict__ b,
        const float* __restrict__ gamma, const float* __restrict__ beta,
        float4* __restrict__ g4) {
    const int lane = threadIdx.x & 63;
    const int n = blockIdx.x * 4 + (threadIdx.x >> 6);   // 25000*4 = 100000
    const int eg = lane >> 3;     // edge slot 0..7
    const int cg = lane & 7;      // channel group: channels cg*8 .. cg*8+7

    const int deg = cnt[n];
    const int dg = deg < SLOT ? deg : SLOT;
    const int base = n * SLOT;
    const float dinv = dinvA[n];

    float a[8];
    if (eg == 0) {                // self-loop term: dinv_n * h_n
        const uint4 hv = hs4[n * 8 + cg];
        const float2 f0 = __half22float2(*(const __half2*)&hv.x);
        const float2 f1 = __half22float2(*(const __half2*)&hv.y);
        const float2 f2 = __half22float2(*(const __half2*)&hv.z);
        const float2 f3 = __half22float2(*(const __half2*)&hv.w);
        a[0] = dinv * f0.x; a[1] = dinv * f0.y; a[2] = dinv * f1.x; a[3] = dinv * f1.y;
        a[4] = dinv * f2.x; a[5] = dinv * f2.y; a[6] = dinv * f3.x; a[7] = dinv * f3.y;
    } else {
#pragma unroll
        for (int i = 0; i < 8; ++i) a[i] = 0.0f;
    }

    for (int j = eg; j < dg; j += 8) {
        const int s = srcs[base + j];
        const float ds = dinvA[s];
        const uint4 hv = hs4[s * 8 + cg];
        const float2 f0 = __half22float2(*(const __half2*)&hv.x);
        const float2 f1 = __half22float2(*(const __half2*)&hv.y);
        const float2 f2 = __half22float2(*(const __half2*)&hv.z);
        const float2 f3 = __half22float2(*(const __half2*)&hv.w);
        a[0] = fmaf(ds, f0.x, a[0]); a[1] = fmaf(ds, f0.y, a[1]);
        a[2] = fmaf(ds, f1.x, a[2]); a[3] = fmaf(ds, f1.y, a[3]);
        a[4] = fmaf(ds, f2.x, a[4]); a[5] = fmaf(ds, f2.y, a[5]);
        a[6] = fmaf(ds, f3.x, a[6]); a[7] = fmaf(ds, f3.y, a[7]);
    }

#pragma unroll
    for (int o = 8; o <= 32; o <<= 1) {
#pragma unroll
        for (int i = 0; i < 8; ++i) a[i] += __shfl_xor(a[i], o);
    }

    const float4* __restrict__ b4 = (const float4*)b;
    const float4 b0 = b4[cg * 2], b1 = b4[cg * 2 + 1];

    float t[8];
    t[0] = dinv * a[0] + b0.x; t[1] = dinv * a[1] + b0.y;
    t[2] = dinv * a[2] + b0.z; t[3] = dinv * a[3] + b0.w;
    t[4] = dinv * a[4] + b1.x; t[5] = dinv * a[5] + b1.y;
    t[6] = dinv * a[6] + b1.z; t[7] = dinv * a[7] + b1.w;

    float s1 = t[0] + t[1] + t[2] + t[3] + t[4] + t[5] + t[6] + t[7];
#pragma unroll
    for (int o = 1; o <= 4; o <<= 1) s1 += __shfl_xor(s1, o);
    const float mu = s1 * (1.0f / 64.0f);

    float d[8], s2 = 0.f;
#pragma unroll
    for (int i = 0; i < 8; ++i) { d[i] = t[i] - mu; s2 = fmaf(d[i], d[i], s2); }
#pragma unroll
    for (int o = 1; o <= 4; o <<= 1) s2 += __shfl_xor(s2, o);
    const float rstd = rsqrtf(s2 * (1.0f / 64.0f) + 1e-5f);

    const float4* __restrict__ gm4 = (const float4*)gamma;
    const float4* __restrict__ bt4 = (const float4*)beta;
    const float4 gm0 = gm4[cg * 2], gm1 = gm4[cg * 2 + 1];
    const float4 bt0 = bt4[cg * 2], bt1 = bt4[cg * 2 + 1];
    const float4 xv0 = x4[n * 16 + cg * 2], xv1 = x4[n * 16 + cg * 2 + 1];

    if (eg == 0) {
        float4 o0, o1;
        o0.x = fmaxf(d[0] * rstd * gm0.x + bt0.x, 0.f) * xv0.x;
        o0.y = fmaxf(d[1] * rstd * gm0.y + bt0.y, 0.f) * xv0.y;
        o0.z = fmaxf(d[2] * rstd * gm0.z + bt0.z, 0.f) * xv0.z;
        o0.w = fmaxf(d[3] * rstd * gm0.w + bt0.w, 0.f) * xv0.w;
        o1.x = fmaxf(d[4] * rstd * gm1.x + bt1.x, 0.f) * xv1.x;
        o1.y = fmaxf(d[5] * rstd * gm1.y + bt1.y, 0.f) * xv1.y;
        o1.z = fmaxf(d[6] * rstd * gm1.z + bt1.z, 0.f) * xv1.z;
        o1.w = fmaxf(d[7] * rstd * gm1.w + bt1.w, 0.f) * xv1.w;
        g4[n * 16 + cg * 2]     = o0;
        g4[n * 16 + cg * 2 + 1] = o1;
    }
}

// ---- out = g @ fcW + fcb: lane-per-row, acc[64], no spill (256,2);
//      g aliases out — each lane only touches its own row ----
__global__ __launch_bounds__(256, 2) void fc_kernel(const float* g,
                                                    const float* __restrict__ fcW,
                                                    const float* __restrict__ fcb,
                                                    float* out) {
    const int lane = threadIdx.x & 63;
    const int wv = blockIdx.x * 4 + (threadIdx.x >> 6);
    const int r = wv * 64 + lane;
    const bool valid = r < N_NODES;
    const float4* g4 = (const float4*)g;

    float acc[C];
#pragma unroll
    for (int m = 0; m < C; ++m) acc[m] = fcb[m];    // uniform → scalar load

#pragma unroll
    for (int kk = 0; kk < 4; ++kk) {
        float4 gv[4];
#pragma unroll
        for (int q = 0; q < 4; ++q)
            gv[q] = valid ? g4[r * 16 + kk * 4 + q] : make_float4(0.f, 0.f, 0.f, 0.f);
#pragma unroll
        for (int j = 0; j < 16; ++j) {
            const float gs = XCOMP(gv[j >> 2], j & 3);
            const float* __restrict__ wr = fcW + (kk * 16 + j) * C;
#pragma unroll
            for (int m = 0; m < C; ++m) acc[m] = fmaf(gs, wr[m], acc[m]);
        }
    }

    if (valid) {
        float4* out4 = (float4*)out;
#pragma unroll
        for (int q = 0; q < 16; ++q)
            out4[r * 16 + q] = make_float4(acc[4 * q], acc[4 * q + 1],
                                           acc[4 * q + 2], acc[4 * q + 3]);
    }
}

extern "C" void kernel_launch(void* const* d_in, const int* in_sizes, int n_in,
                              void* d_out, int out_size, void* d_ws, size_t ws_size,
                              hipStream_t stream) {
    const float* x     = (const float*)d_in[0];
    const int*   ei    = (const int*)d_in[1];
    const float* W     = (const float*)d_in[2];
    const float* b     = (const float*)d_in[3];
    const float* gamma = (const float*)d_in[4];
    const float* beta  = (const float*)d_in[5];
    const float* fcW   = (const float*)d_in[6];
    const float* fcb   = (const float*)d_in[7];
    float* out = (float*)d_out;

    const int* srcI = ei;
    const int* dstI = ei + N_EDGES;

    // workspace layout (~30 MB)
    int*      cur   = (int*)d_ws;                   // NB*16 padded cursors (8192 ints)
    unsigned* bdata = (unsigned*)(cur + 8192);      // NB*CAP words (4.0 MB)
    int*      srcs  = (int*)(bdata + NB * CAP);     // N_NODES*SLOT (12.8 MB)
    int*      cnt   = srcs + N_NODES * SLOT;        // 100352
    float*    dinv  = (float*)(cnt + 100352);       // 100352
    uint4*    hs4   = (uint4*)(dinv + 100352);      // N_NODES*C fp16 (12.8 MB)

    float* g = out;                                 // gated activation aliases d_out

    hipMemsetAsync(cur, 0, NB * 16 * sizeof(int), stream);

    scatter_xw_kernel<<<SC_BLOCKS + XW_BLOCKS, 256, 0, stream>>>(srcI, dstI, cur,
                                                                 bdata, x, W, hs4);

    bin_kernel<<<NB, 256, 0, stream>>>(cur, bdata, srcs, cnt, dinv);

    gather_ln_kernel<<<N_NODES / 4, 256, 0, stream>>>(hs4, cnt, dinv, srcs,
                                                      (const float4*)x, b, gamma,
                                                      beta, (float4*)g);

    fc_kernel<<<XW_BLOCKS, 256, 0, stream>>>(g, fcW, fcb, out);
}